// Round 1
// baseline (1184.910 us; speedup 1.0000x reference)
//
#include <hip/hip_runtime.h>

// Problem constants (fixed by reference)
#define NE 8
#define TT 2048            // tokens per expert
#define KD 2048            // INPUT_SIZE  (K)
#define ND 8192            // OUTPUT_SIZE (N)
#define MT (NE * TT)       // 16384 total rows
#define NW ((size_t)NE * ND * KD)   // 134217728 weight elems
#define NX ((size_t)MT * KD)        // 33554432 input elems

typedef _Float16 f16;
typedef _Float16 f16x4 __attribute__((ext_vector_type(4)));
typedef _Float16 f16x8 __attribute__((ext_vector_type(8)));
typedef float    f32x4 __attribute__((ext_vector_type(4)));

// ---------------- K1: partial abs-sum (f64, deterministic) ----------------
__global__ void k_abs_partial(const float* __restrict__ w, double* __restrict__ part) {
    __shared__ double sred[256];
    const size_t n4 = NW / 4;
    const size_t stride = (size_t)gridDim.x * blockDim.x;
    double acc = 0.0;
    for (size_t i = (size_t)blockIdx.x * blockDim.x + threadIdx.x; i < n4; i += stride) {
        float4 v = ((const float4*)w)[i];
        acc += (double)fabsf(v.x) + (double)fabsf(v.y) + (double)fabsf(v.z) + (double)fabsf(v.w);
    }
    sred[threadIdx.x] = acc;
    __syncthreads();
    for (int s = 128; s > 0; s >>= 1) {
        if ((int)threadIdx.x < s) sred[threadIdx.x] += sred[threadIdx.x + s];
        __syncthreads();
    }
    if (threadIdx.x == 0) part[blockIdx.x] = sred[0];
}

// ---------------- K2: finalize scale ----------------
__global__ void k_finalize(const double* __restrict__ part, double* __restrict__ sc) {
    __shared__ double sred[256];
    double a = 0.0;
    for (int i = threadIdx.x; i < 2048; i += 256) a += part[i];
    sred[threadIdx.x] = a;
    __syncthreads();
    for (int s = 128; s > 0; s >>= 1) {
        if ((int)threadIdx.x < s) sred[threadIdx.x] += sred[threadIdx.x + s];
        __syncthreads();
    }
    if (threadIdx.x == 0) {
        double mean = sred[0] / (double)NW;
        double denom = mean > 1e-5 ? mean : 1e-5;
        sc[0] = 1.0 / denom;   // scale
        sc[1] = denom;         // 1/scale (output multiplier)
    }
}

// ---------------- K3: quantize w -> ternary f16 ----------------
__global__ void k_quant(const float* __restrict__ w, const double* __restrict__ sc,
                        f16* __restrict__ q) {
    const double scale = sc[0];
    const size_t n4 = NW / 4;
    const size_t stride = (size_t)gridDim.x * blockDim.x;
    for (size_t i = (size_t)blockIdx.x * blockDim.x + threadIdx.x; i < n4; i += stride) {
        float4 v = ((const float4*)w)[i];
        f16x4 o;
        o[0] = (f16)(float)fmin(fmax(rint((double)v.x * scale), -1.0), 1.0);
        o[1] = (f16)(float)fmin(fmax(rint((double)v.y * scale), -1.0), 1.0);
        o[2] = (f16)(float)fmin(fmax(rint((double)v.z * scale), -1.0), 1.0);
        o[3] = (f16)(float)fmin(fmax(rint((double)v.w * scale), -1.0), 1.0);
        ((f16x4*)q)[i] = o;
    }
}

// ---------------- K4: x f32 -> f16 ----------------
__global__ void k_xconv(const float* __restrict__ x, f16* __restrict__ xh) {
    const size_t n4 = NX / 4;
    const size_t stride = (size_t)gridDim.x * blockDim.x;
    for (size_t i = (size_t)blockIdx.x * blockDim.x + threadIdx.x; i < n4; i += stride) {
        float4 v = ((const float4*)x)[i];
        f16x4 o;
        o[0] = (f16)v.x; o[1] = (f16)v.y; o[2] = (f16)v.z; o[3] = (f16)v.w;
        ((f16x4*)xh)[i] = o;
    }
}

// ---------------- K5: grouped GEMM, 128x128x64, f16 MFMA ----------------
#define BM 128
#define BN 128
#define BK 64

__device__ __forceinline__ void gload16(const void* g, void* l) {
    __builtin_amdgcn_global_load_lds(
        (const __attribute__((address_space(1))) unsigned int*)g,
        (__attribute__((address_space(3))) unsigned int*)l, 16, 0, 0);
}

__global__ __launch_bounds__(256)
void k_gemm(const f16* __restrict__ xh, const f16* __restrict__ qh,
            const double* __restrict__ sc, float* __restrict__ out) {
    __shared__ f16 sA[BM * BK];   // 16 KiB, XOR-swizzled physical layout
    __shared__ f16 sB[BN * BK];   // 16 KiB

    const int lane = threadIdx.x & 63;
    const int wid  = threadIdx.x >> 6;
    const int wr   = wid >> 1;       // wave row (0..1) -> 64-row strip
    const int wc   = wid & 1;        // wave col (0..1) -> 64-col strip

    // XCD-aware swizzle: nwg = 8*16*64 = 8192, divisible by 8
    const int nwg = NE * (TT / BM) * (ND / BN);
    const int cpx = nwg >> 3;
    const int wg  = (blockIdx.x & 7) * cpx + (blockIdx.x >> 3);
    const int e   = wg >> 10;         // / 1024
    const int rem = wg & 1023;
    const int mt  = rem >> 6;         // 0..15
    const int nt  = rem & 63;         // 0..63

    const f16* Abase = xh + ((size_t)e * TT + (size_t)mt * BM) * KD;
    const f16* Bbase = qh + ((size_t)e * ND + (size_t)nt * BN) * KD;
    float*     Cbase = out + ((size_t)e * TT + (size_t)mt * BM) * ND + (size_t)nt * BN;

    f32x4 acc[4][4];
#pragma unroll
    for (int m = 0; m < 4; ++m)
#pragma unroll
        for (int n = 0; n < 4; ++n) acc[m][n] = (f32x4){0.f, 0.f, 0.f, 0.f};

    for (int kt = 0; kt < KD / BK; ++kt) {
        // ---- stage: global -> LDS, linear dest + inverse-swizzled source ----
#pragma unroll
        for (int j = 0; j < 4; ++j) {
            const int chunk = wid * 4 + j;                 // 16 x 1KiB chunks
            const int offP  = chunk * 1024 + lane * 16;    // physical LDS byte
            const int srcL  = offP ^ (((offP >> 7) & 7) << 4);  // logical byte
            const int r  = srcL >> 7;          // tile row
            const int cb = srcL & 127;         // byte within row (k*2)
            gload16(Abase + (size_t)r * KD + kt * BK + (cb >> 1),
                    (char*)sA + chunk * 1024);
            gload16(Bbase + (size_t)r * KD + kt * BK + (cb >> 1),
                    (char*)sB + chunk * 1024);
        }
        __syncthreads();   // compiler emits vmcnt(0) drain before barrier

        // ---- compute: 2 k-slices x 16 MFMA ----
#pragma unroll
        for (int ks = 0; ks < 2; ++ks) {
            f16x8 af[4], bf[4];
#pragma unroll
            for (int m = 0; m < 4; ++m) {
                const int r = wr * 64 + m * 16 + (lane & 15);
                int b = (r << 7) + ks * 64 + ((lane >> 4) << 4);
                b ^= ((r & 7) << 4);
                af[m] = *(const f16x8*)((const char*)sA + b);
            }
#pragma unroll
            for (int n = 0; n < 4; ++n) {
                const int r = wc * 64 + n * 16 + (lane & 15);
                int b = (r << 7) + ks * 64 + ((lane >> 4) << 4);
                b ^= ((r & 7) << 4);
                bf[n] = *(const f16x8*)((const char*)sB + b);
            }
#pragma unroll
            for (int m = 0; m < 4; ++m)
#pragma unroll
                for (int n = 0; n < 4; ++n)
                    acc[m][n] = __builtin_amdgcn_mfma_f32_16x16x32_f16(
                        af[m], bf[n], acc[m][n], 0, 0, 0);
        }
        __syncthreads();
    }

    // ---- epilogue: scale by s = 1/scale, f32 store ----
    const float s = (float)sc[1];
#pragma unroll
    for (int m = 0; m < 4; ++m)
#pragma unroll
        for (int n = 0; n < 4; ++n)
#pragma unroll
            for (int r4 = 0; r4 < 4; ++r4) {
                const int row = wr * 64 + m * 16 + (lane >> 4) * 4 + r4;
                const int col = wc * 64 + n * 16 + (lane & 15);
                Cbase[(size_t)row * ND + col] = acc[m][n][r4] * s;
            }
}

// ---------------- fallback (only if ws too small): f32 tiled, on-the-fly quant ----------------
__global__ void k_fallback(const float* __restrict__ x, const float* __restrict__ w,
                           const double* __restrict__ sc, float* __restrict__ out) {
    const int row0 = blockIdx.x * 16;
    const int col0 = blockIdx.y * 16;
    const int e = row0 / TT;
    __shared__ float xs[16][17];
    __shared__ float wq[16][17];
    const double scale = sc[0];
    const float s = (float)sc[1];
    const int tx = threadIdx.x, ty = threadIdx.y;
    const float* wbase = w + ((size_t)e * ND + col0) * KD;
    float acc = 0.f;
    for (int k0 = 0; k0 < KD; k0 += 16) {
        xs[ty][tx] = x[(size_t)(row0 + ty) * KD + k0 + tx];
        const float wv = wbase[(size_t)ty * KD + k0 + tx];
        wq[ty][tx] = (float)fmin(fmax(rint((double)wv * scale), -1.0), 1.0);
        __syncthreads();
#pragma unroll
        for (int kk = 0; kk < 16; ++kk) acc += xs[ty][kk] * wq[tx][kk];
        __syncthreads();
    }
    out[(size_t)(row0 + ty) * ND + col0 + tx] = acc * s;
}

// ---------------- launch ----------------
extern "C" void kernel_launch(void* const* d_in, const int* in_sizes, int n_in,
                              void* d_out, int out_size, void* d_ws, size_t ws_size,
                              hipStream_t stream) {
    const float* x = (const float*)d_in[0];
    const float* w = (const float*)d_in[1];
    float* out = (float*)d_out;

    double* part = (double*)d_ws;                       // 2048 * 8 B
    double* sc   = (double*)((char*)d_ws + 16384);      // [0]=scale, [1]=1/scale

    const size_t need = 65536 + NX * 2 + NW * 2;        // ~320 MiB

    hipLaunchKernelGGL(k_abs_partial, dim3(2048), dim3(256), 0, stream, w, part);
    hipLaunchKernelGGL(k_finalize,   dim3(1),    dim3(256), 0, stream, part, sc);

    if (ws_size >= need) {
        f16* xh = (f16*)((char*)d_ws + 65536);
        f16* qh = (f16*)((char*)d_ws + 65536 + NX * 2);
        hipLaunchKernelGGL(k_quant, dim3(2048), dim3(256), 0, stream, w, sc, qh);
        hipLaunchKernelGGL(k_xconv, dim3(2048), dim3(256), 0, stream, x, xh);
        hipLaunchKernelGGL(k_gemm,  dim3(NE * (TT / BM) * (ND / BN)), dim3(256), 0, stream,
                           xh, qh, sc, out);
    } else {
        dim3 grid(MT / 16, ND / 16);
        hipLaunchKernelGGL(k_fallback, grid, dim3(16, 16), 0, stream, x, w, sc, out);
    }
}

// Round 2
// 951.657 us; speedup vs baseline: 1.2451x; 1.2451x over previous
//
#include <hip/hip_runtime.h>

// Problem constants (fixed by reference)
#define NE 8
#define TT 2048            // tokens per expert
#define KD 2048            // INPUT_SIZE  (K)
#define ND 8192            // OUTPUT_SIZE (N)
#define MT (NE * TT)       // 16384 total rows
#define NW ((size_t)NE * ND * KD)   // 134217728 weight elems
#define NX ((size_t)MT * KD)        // 33554432 input elems

typedef _Float16 f16;
typedef _Float16 f16x4 __attribute__((ext_vector_type(4)));
typedef _Float16 f16x8 __attribute__((ext_vector_type(8)));
typedef float    f32x4 __attribute__((ext_vector_type(4)));

// ---------------- K1: partial abs-sum (f64, deterministic) ----------------
__global__ void k_abs_partial(const float* __restrict__ w, double* __restrict__ part) {
    __shared__ double sred[256];
    const size_t n4 = NW / 4;
    const size_t stride = (size_t)gridDim.x * blockDim.x;
    double acc = 0.0;
    for (size_t i = (size_t)blockIdx.x * blockDim.x + threadIdx.x; i < n4; i += stride) {
        float4 v = ((const float4*)w)[i];
        acc += (double)fabsf(v.x) + (double)fabsf(v.y) + (double)fabsf(v.z) + (double)fabsf(v.w);
    }
    sred[threadIdx.x] = acc;
    __syncthreads();
    for (int s = 128; s > 0; s >>= 1) {
        if ((int)threadIdx.x < s) sred[threadIdx.x] += sred[threadIdx.x + s];
        __syncthreads();
    }
    if (threadIdx.x == 0) part[blockIdx.x] = sred[0];
}

// ---------------- K2: finalize scale ----------------
__global__ void k_finalize(const double* __restrict__ part, double* __restrict__ sc) {
    __shared__ double sred[256];
    double a = 0.0;
    for (int i = threadIdx.x; i < 2048; i += 256) a += part[i];
    sred[threadIdx.x] = a;
    __syncthreads();
    for (int s = 128; s > 0; s >>= 1) {
        if ((int)threadIdx.x < s) sred[threadIdx.x] += sred[threadIdx.x + s];
        __syncthreads();
    }
    if (threadIdx.x == 0) {
        double mean = sred[0] / (double)NW;
        double denom = mean > 1e-5 ? mean : 1e-5;
        sc[0] = 1.0 / denom;   // scale
        sc[1] = denom;         // 1/scale (output multiplier)
    }
}

// ---------------- K3: quantize w -> ternary f16 ----------------
__global__ void k_quant(const float* __restrict__ w, const double* __restrict__ sc,
                        f16* __restrict__ q) {
    const double scale = sc[0];
    const size_t n4 = NW / 4;
    const size_t stride = (size_t)gridDim.x * blockDim.x;
    for (size_t i = (size_t)blockIdx.x * blockDim.x + threadIdx.x; i < n4; i += stride) {
        float4 v = ((const float4*)w)[i];
        f16x4 o;
        o[0] = (f16)(float)fmin(fmax(rint((double)v.x * scale), -1.0), 1.0);
        o[1] = (f16)(float)fmin(fmax(rint((double)v.y * scale), -1.0), 1.0);
        o[2] = (f16)(float)fmin(fmax(rint((double)v.z * scale), -1.0), 1.0);
        o[3] = (f16)(float)fmin(fmax(rint((double)v.w * scale), -1.0), 1.0);
        ((f16x4*)q)[i] = o;
    }
}

// ---------------- K4: x f32 -> f16 ----------------
__global__ void k_xconv(const float* __restrict__ x, f16* __restrict__ xh) {
    const size_t n4 = NX / 4;
    const size_t stride = (size_t)gridDim.x * blockDim.x;
    for (size_t i = (size_t)blockIdx.x * blockDim.x + threadIdx.x; i < n4; i += stride) {
        float4 v = ((const float4*)x)[i];
        f16x4 o;
        o[0] = (f16)v.x; o[1] = (f16)v.y; o[2] = (f16)v.z; o[3] = (f16)v.w;
        ((f16x4*)xh)[i] = o;
    }
}

// ---------------- K5: grouped GEMM, 256x256x32, ring-4 LDS, counted vmcnt ----
// 8 waves (2 M x 4 N), per-wave output 128x64, mfma_f32_16x16x32_f16.
// Ring-4 double... quad-buffer: stage(t+2) issued at iter t start overwrites
// tile t-2 (reads finished two barriers ago -> race-free). vmcnt(8) leaves the
// 2 newest stages (4 gloads each) in flight; never drains to 0 in the loop.
#define BK 32
#define NTK (KD / BK)   // 64 K-tiles

__device__ __forceinline__ void gload16(const void* g, void* l) {
    __builtin_amdgcn_global_load_lds(
        (const __attribute__((address_space(1))) unsigned int*)g,
        (__attribute__((address_space(3))) unsigned int*)l, 16, 0, 0);
}

__global__ __launch_bounds__(512, 2)
void k_gemm(const f16* __restrict__ xh, const f16* __restrict__ qh,
            const double* __restrict__ sc, float* __restrict__ out) {
    // [buf][A:16KiB | B:16KiB], 4 bufs = 128 KiB
    __shared__ char lds[4 * 32768];

    const int lane = (int)threadIdx.x & 63;
    const int wid  = (int)threadIdx.x >> 6;   // 0..7
    const int wr   = wid >> 2;                 // 0..1  (M strip of 128)
    const int wc   = wid & 3;                  // 0..3  (N strip of 64)
    const int li   = lane & 15;
    const int sl   = lane >> 4;                // 0..3 (k-slot, 8 f16 each)

    // XCD-aware swizzle: nwg = 2048, divisible by 8
    const int wg = ((int)blockIdx.x & 7) * 256 + ((int)blockIdx.x >> 3);
    const int e  = wg >> 8;                    // expert = XCD
    const int u  = wg & 255;
    const int mt = (u >> 1) & 7;               // 0..7
    const int nt = (((u >> 4) << 1) | (u & 1));// 0..31  (2-wide nt windows)

    const f16* Ab = xh + ((size_t)e * TT + (size_t)mt * 256) * KD;
    const f16* Bb = qh + ((size_t)e * ND + (size_t)nt * 256) * KD;
    float*     Cb = out + ((size_t)e * TT + (size_t)mt * 256) * ND + (size_t)nt * 256;

    // load output scale up front, then drain vmcnt so the counted waits below
    // see only the staging loads
    const float sfac = (float)sc[1];
    asm volatile("s_waitcnt vmcnt(0)" ::: "memory");

    f32x4 acc[8][4];
#pragma unroll
    for (int m = 0; m < 8; ++m)
#pragma unroll
        for (int n = 0; n < 4; ++n) acc[m][n] = (f32x4){0.f, 0.f, 0.f, 0.f};

    // stage one K-tile (A 16 KiB + B 16 KiB) into buf t&3: 4 gloads/thread.
    // Linear LDS dest, inverse-swizzled global source (swizzle: byte ^= (row&3)<<4).
    auto stage = [&](int t) {
        char* LA = lds + (t & 3) * 32768;
        char* LB = LA + 16384;
#pragma unroll
        for (int g = 0; g < 2; ++g) {
            const int bp = (g * 8 + wid) * 1024;           // wave-uniform LDS base
            const int r  = (bp >> 6) + (lane >> 2);        // tile row 0..255
            const int ko = (((lane & 3) ^ (r & 3)) << 3) + t * BK;  // k elem
            gload16(Ab + (size_t)r * KD + ko, LA + bp);
            gload16(Bb + (size_t)r * KD + ko, LB + bp);
        }
    };

    auto compute = [&](int t) {
        const char* LA = lds + (t & 3) * 32768;
        const char* LB = LA + 16384;
        f16x8 bfr[4], afr[8];
#pragma unroll
        for (int n = 0; n < 4; ++n) {
            const int r = wc * 64 + n * 16 + li;
            bfr[n] = *(const f16x8*)(LB + (r << 6) + (((sl ^ (r & 3)) & 3) << 4));
        }
#pragma unroll
        for (int m = 0; m < 8; ++m) {
            const int r = wr * 128 + m * 16 + li;
            afr[m] = *(const f16x8*)(LA + (r << 6) + (((sl ^ (r & 3)) & 3) << 4));
        }
        __builtin_amdgcn_s_setprio(1);
#pragma unroll
        for (int m = 0; m < 8; ++m)
#pragma unroll
            for (int n = 0; n < 4; ++n)
                acc[m][n] = __builtin_amdgcn_mfma_f32_16x16x32_f16(
                    afr[m], bfr[n], acc[m][n], 0, 0, 0);
        __builtin_amdgcn_s_setprio(0);
    };

    // prologue: 2 tiles in flight
    stage(0);
    stage(1);

    for (int t = 0; t < NTK - 2; ++t) {
        stage(t + 2);
        asm volatile("s_waitcnt vmcnt(8)" ::: "memory");  // tile t landed (own lanes)
        __builtin_amdgcn_s_barrier();                      // all waves' tile t landed
        __builtin_amdgcn_sched_barrier(0);                 // pin ds_reads below barrier
        compute(t);
    }
    asm volatile("s_waitcnt vmcnt(4)" ::: "memory");
    __builtin_amdgcn_s_barrier();
    __builtin_amdgcn_sched_barrier(0);
    compute(NTK - 2);
    asm volatile("s_waitcnt vmcnt(0)" ::: "memory");
    __builtin_amdgcn_s_barrier();
    __builtin_amdgcn_sched_barrier(0);
    compute(NTK - 1);

    // ---- epilogue: scale by 1/scale, f32 store ----
#pragma unroll
    for (int m = 0; m < 8; ++m)
#pragma unroll
        for (int n = 0; n < 4; ++n)
#pragma unroll
            for (int r4 = 0; r4 < 4; ++r4) {
                const int row = wr * 128 + m * 16 + sl * 4 + r4;
                const int col = wc * 64 + n * 16 + li;
                Cb[(size_t)row * ND + col] = acc[m][n][r4] * sfac;
            }
}

// ---------------- fallback (only if ws too small): f32 tiled, on-the-fly quant ----------------
__global__ void k_fallback(const float* __restrict__ x, const float* __restrict__ w,
                           const double* __restrict__ sc, float* __restrict__ out) {
    const int row0 = blockIdx.x * 16;
    const int col0 = blockIdx.y * 16;
    const int e = row0 / TT;
    __shared__ float xs[16][17];
    __shared__ float wq[16][17];
    const double scale = sc[0];
    const float s = (float)sc[1];
    const int tx = threadIdx.x, ty = threadIdx.y;
    const float* wbase = w + ((size_t)e * ND + col0) * KD;
    float acc = 0.f;
    for (int k0 = 0; k0 < KD; k0 += 16) {
        xs[ty][tx] = x[(size_t)(row0 + ty) * KD + k0 + tx];
        const float wv = wbase[(size_t)ty * KD + k0 + tx];
        wq[ty][tx] = (float)fmin(fmax(rint((double)wv * scale), -1.0), 1.0);
        __syncthreads();
#pragma unroll
        for (int kk = 0; kk < 16; ++kk) acc += xs[ty][kk] * wq[tx][kk];
        __syncthreads();
    }
    out[(size_t)(row0 + ty) * ND + col0 + tx] = acc * s;
}

// ---------------- launch ----------------
extern "C" void kernel_launch(void* const* d_in, const int* in_sizes, int n_in,
                              void* d_out, int out_size, void* d_ws, size_t ws_size,
                              hipStream_t stream) {
    const float* x = (const float*)d_in[0];
    const float* w = (const float*)d_in[1];
    float* out = (float*)d_out;

    double* part = (double*)d_ws;                       // 2048 * 8 B
    double* sc   = (double*)((char*)d_ws + 16384);      // [0]=scale, [1]=1/scale

    const size_t need = 65536 + NX * 2 + NW * 2;        // ~320 MiB

    hipLaunchKernelGGL(k_abs_partial, dim3(2048), dim3(256), 0, stream, w, part);
    hipLaunchKernelGGL(k_finalize,   dim3(1),    dim3(256), 0, stream, part, sc);

    if (ws_size >= need) {
        f16* xh = (f16*)((char*)d_ws + 65536);
        f16* qh = (f16*)((char*)d_ws + 65536 + NX * 2);
        hipLaunchKernelGGL(k_quant, dim3(2048), dim3(256), 0, stream, w, sc, qh);
        hipLaunchKernelGGL(k_xconv, dim3(2048), dim3(256), 0, stream, x, xh);
        hipLaunchKernelGGL(k_gemm,  dim3(NE * (TT / 256) * (ND / 256)), dim3(512), 0, stream,
                           xh, qh, sc, out);
    } else {
        dim3 grid(MT / 16, ND / 16);
        hipLaunchKernelGGL(k_fallback, grid, dim3(16, 16), 0, stream, x, w, sc, out);
    }
}

// Round 3
// 905.996 us; speedup vs baseline: 1.3079x; 1.0504x over previous
//
#include <hip/hip_runtime.h>

// Problem constants (fixed by reference)
#define NE 8
#define TT 2048            // tokens per expert
#define KD 2048            // INPUT_SIZE  (K)
#define ND 8192            // OUTPUT_SIZE (N)
#define MT (NE * TT)       // 16384 total rows
#define NW ((size_t)NE * ND * KD)   // 134217728 weight elems
#define NX ((size_t)MT * KD)        // 33554432 input elems

typedef _Float16 f16;
typedef _Float16 f16x4 __attribute__((ext_vector_type(4)));
typedef _Float16 f16x8 __attribute__((ext_vector_type(8)));
typedef float    f32x4 __attribute__((ext_vector_type(4)));

// ---------------- K1: partial abs-sum (f64, deterministic) ----------------
__global__ void k_abs_partial(const float* __restrict__ w, double* __restrict__ part) {
    __shared__ double sred[256];
    const size_t n4 = NW / 4;
    const size_t stride = (size_t)gridDim.x * blockDim.x;
    double acc = 0.0;
    for (size_t i = (size_t)blockIdx.x * blockDim.x + threadIdx.x; i < n4; i += stride) {
        float4 v = ((const float4*)w)[i];
        acc += (double)fabsf(v.x) + (double)fabsf(v.y) + (double)fabsf(v.z) + (double)fabsf(v.w);
    }
    sred[threadIdx.x] = acc;
    __syncthreads();
    for (int s = 128; s > 0; s >>= 1) {
        if ((int)threadIdx.x < s) sred[threadIdx.x] += sred[threadIdx.x + s];
        __syncthreads();
    }
    if (threadIdx.x == 0) part[blockIdx.x] = sred[0];
}

// ---------------- K2: finalize scale ----------------
__global__ void k_finalize(const double* __restrict__ part, double* __restrict__ sc) {
    __shared__ double sred[256];
    double a = 0.0;
    for (int i = threadIdx.x; i < 2048; i += 256) a += part[i];
    sred[threadIdx.x] = a;
    __syncthreads();
    for (int s = 128; s > 0; s >>= 1) {
        if ((int)threadIdx.x < s) sred[threadIdx.x] += sred[threadIdx.x + s];
        __syncthreads();
    }
    if (threadIdx.x == 0) {
        double mean = sred[0] / (double)NW;
        double denom = mean > 1e-5 ? mean : 1e-5;
        sc[0] = 1.0 / denom;   // scale
        sc[1] = denom;         // 1/scale (output multiplier)
    }
}

// ---------------- K3: quantize w -> ternary f16 ----------------
__global__ void k_quant(const float* __restrict__ w, const double* __restrict__ sc,
                        f16* __restrict__ q) {
    const double scale = sc[0];
    const size_t n4 = NW / 4;
    const size_t stride = (size_t)gridDim.x * blockDim.x;
    for (size_t i = (size_t)blockIdx.x * blockDim.x + threadIdx.x; i < n4; i += stride) {
        float4 v = ((const float4*)w)[i];
        f16x4 o;
        o[0] = (f16)(float)fmin(fmax(rint((double)v.x * scale), -1.0), 1.0);
        o[1] = (f16)(float)fmin(fmax(rint((double)v.y * scale), -1.0), 1.0);
        o[2] = (f16)(float)fmin(fmax(rint((double)v.z * scale), -1.0), 1.0);
        o[3] = (f16)(float)fmin(fmax(rint((double)v.w * scale), -1.0), 1.0);
        ((f16x4*)q)[i] = o;
    }
}

// ---------------- K4: x f32 -> f16 ----------------
__global__ void k_xconv(const float* __restrict__ x, f16* __restrict__ xh) {
    const size_t n4 = NX / 4;
    const size_t stride = (size_t)gridDim.x * blockDim.x;
    for (size_t i = (size_t)blockIdx.x * blockDim.x + threadIdx.x; i < n4; i += stride) {
        float4 v = ((const float4*)x)[i];
        f16x4 o;
        o[0] = (f16)v.x; o[1] = (f16)v.y; o[2] = (f16)v.z; o[3] = (f16)v.w;
        ((f16x4*)xh)[i] = o;
    }
}

// ---------------- K5: grouped GEMM, 256x256x64, 8-phase schedule ----------
// m201-style: 8 waves (2M x 4N), per-wave 128x64, double-buffered LDS
// (2 bufs x [Ak0|Ak1|Bk0|Bk1] x 16 KiB = 128 KiB). 4 phases per K-tile(64):
//   phase = { 4-8 ds_read_b128 | 2 global_load_lds (one half of tile t+1)
//             | s_barrier | lgkmcnt(0)+sched_barrier | setprio(1) 16 MFMA
//             setprio(0) | [vmcnt(4) at P1/P3] s_barrier }
// Counted vmcnt(4): at every end-P1/end-P3 exactly 8 loads are outstanding;
// keeping the 4 newest guarantees the halves needed 1 phase later landed.
// LDS swizzle (64-B rows): physslot = slot ^ (r&3) ^ ((r>>2)&3)  -- any 8
// consecutive lanes hit 8 distinct 4-bank groups -> conflict-free.
#define NTK 32   // KD / 64

__device__ __forceinline__ void gload16(const void* g, void* l) {
    __builtin_amdgcn_global_load_lds(
        (const __attribute__((address_space(1))) unsigned int*)g,
        (__attribute__((address_space(3))) unsigned int*)l, 16, 0, 0);
}

#define BAR() __builtin_amdgcn_s_barrier()
#define LGKM0() do { asm volatile("s_waitcnt lgkmcnt(0)" ::: "memory"); \
                     __builtin_amdgcn_sched_barrier(0); } while (0)
#define VM(N) asm volatile("s_waitcnt vmcnt(" #N ")" ::: "memory")

#define RD_A(LA_, MOFF) { \
  _Pragma("unroll") for (int i_ = 0; i_ < 4; ++i_) { \
    const int r_ = wr * 128 + (MOFF) + i_ * 16 + li; \
    const int p_ = (sl ^ (r_ & 3) ^ ((r_ >> 2) & 3)) & 3; \
    af[i_] = *(const f16x8*)((LA_) + (r_ << 6) + (p_ << 4)); } }

#define RD_B(LB_) { \
  _Pragma("unroll") for (int i_ = 0; i_ < 4; ++i_) { \
    const int r_ = wc * 64 + i_ * 16 + li; \
    const int p_ = (sl ^ (r_ & 3) ^ ((r_ >> 2) & 3)) & 3; \
    bf[i_] = *(const f16x8*)((LB_) + (r_ << 6) + (p_ << 4)); } }

#define MFMA_Q(MB) { \
  __builtin_amdgcn_s_setprio(1); \
  _Pragma("unroll") for (int m_ = 0; m_ < 4; ++m_) \
    _Pragma("unroll") for (int n_ = 0; n_ < 4; ++n_) \
      acc[(MB) + m_][n_] = __builtin_amdgcn_mfma_f32_16x16x32_f16( \
          af[m_], bf[n_], acc[(MB) + m_][n_], 0, 0, 0); \
  __builtin_amdgcn_s_setprio(0); }

__global__ __launch_bounds__(512, 2)
void k_gemm(const f16* __restrict__ xh, const f16* __restrict__ qh,
            const double* __restrict__ sc, float* __restrict__ out) {
    __shared__ char lds[2 * 65536];

    const int lane = (int)threadIdx.x & 63;
    const int wid  = (int)threadIdx.x >> 6;   // 0..7
    const int wr   = wid >> 2;                 // 0..1  (M strip of 128)
    const int wc   = wid & 3;                  // 0..3  (N strip of 64)
    const int li   = lane & 15;
    const int sl   = lane >> 4;                // k-slot 0..3

    // XCD-aware swizzle: nwg = 2048, divisible by 8
    const int wg = ((int)blockIdx.x & 7) * 256 + ((int)blockIdx.x >> 3);
    const int e  = wg >> 8;
    const int u  = wg & 255;
    const int mt = (u >> 1) & 7;
    const int nt = (((u >> 4) << 1) | (u & 1));

    const f16* Ab = xh + ((size_t)e * TT + (size_t)mt * 256) * KD;
    const f16* Bb = qh + ((size_t)e * ND + (size_t)nt * 256) * KD;
    float*     Cb = out + ((size_t)e * TT + (size_t)mt * 256) * ND + (size_t)nt * 256;

    const float sfac = (float)sc[1];
    asm volatile("s_waitcnt vmcnt(0)" ::: "memory");

    // staging per-thread precompute (chunk = 1 KiB, 2 chunks/thread per half)
    const int lslot = (lane & 3) ^ ((lane >> 2) & 3) ^ ((lane >> 4) & 3);
    size_t sele[2]; int coff[2];
#pragma unroll
    for (int g = 0; g < 2; ++g) {
        const int chunk = (wid << 1) | g;              // 0..15
        const int srow  = chunk * 16 + (lane >> 2);    // 0..255
        sele[g] = (size_t)srow * KD + lslot * 8;
        coff[g] = chunk * 1024;                         // wave-uniform
    }
    // stage one 16-KiB half: matrix base, region byte offset, dest buf, k elem off
    auto stage = [&](const f16* base, int region, char* sbuf, int koff) {
#pragma unroll
        for (int g = 0; g < 2; ++g)
            gload16(base + sele[g] + koff, sbuf + region + coff[g]);
    };

    f32x4 acc[8][4];
#pragma unroll
    for (int m = 0; m < 8; ++m)
#pragma unroll
        for (int n = 0; n < 4; ++n) acc[m][n] = (f32x4){0.f, 0.f, 0.f, 0.f};

    f16x8 af[4], bf[4];

    // prologue: stage tile 0 fully (A0,B0,A1,B1), wait for A0+B0
    stage(Ab, 0,     lds, 0);
    stage(Bb, 32768, lds, 0);
    stage(Ab, 16384, lds, 32);
    stage(Bb, 49152, lds, 32);
    VM(4);
    BAR();

    for (int t = 0; t < NTK - 1; ++t) {
        const char* L = lds + (t & 1) * 65536;
        char*       S = lds + ((t & 1) ^ 1) * 65536;
        const int k1 = (t + 1) * 64;
        // P0: reads Ak0,Bk0 | stage Ak0(t+1)
        RD_A(L, 0); RD_B(L + 32768);
        stage(Ab, 0, S, k1);
        BAR(); LGKM0(); MFMA_Q(0); BAR();
        // P1: reads Ak0 upper | stage Bk0(t+1) | vmcnt(4)
        RD_A(L, 64);
        stage(Bb, 32768, S, k1);
        BAR(); LGKM0(); MFMA_Q(4); VM(4); BAR();
        // P2: reads Ak1,Bk1 | stage Ak1(t+1)
        RD_A(L + 16384, 0); RD_B(L + 49152);
        stage(Ab, 16384, S, k1 + 32);
        BAR(); LGKM0(); MFMA_Q(0); BAR();
        // P3: reads Ak1 upper | stage Bk1(t+1) | vmcnt(4)
        RD_A(L + 16384, 64);
        stage(Bb, 49152, S, k1 + 32);
        BAR(); LGKM0(); MFMA_Q(4); VM(4); BAR();
    }
    // tail tile (no staging): drain remaining 2 halves at end-P1
    {
        const char* L = lds + ((NTK - 1) & 1) * 65536;
        RD_A(L, 0); RD_B(L + 32768);
        BAR(); LGKM0(); MFMA_Q(0); BAR();
        RD_A(L, 64);
        BAR(); LGKM0(); MFMA_Q(4); VM(0); BAR();
        RD_A(L + 16384, 0); RD_B(L + 49152);
        BAR(); LGKM0(); MFMA_Q(0); BAR();
        RD_A(L + 16384, 64);
        BAR(); LGKM0(); MFMA_Q(4);
    }

    // ---- epilogue: scale by 1/scale, f32 store ----
#pragma unroll
    for (int m = 0; m < 8; ++m)
#pragma unroll
        for (int n = 0; n < 4; ++n)
#pragma unroll
            for (int r4 = 0; r4 < 4; ++r4) {
                const int row = wr * 128 + m * 16 + sl * 4 + r4;
                const int col = wc * 64 + n * 16 + li;
                Cb[(size_t)row * ND + col] = acc[m][n][r4] * sfac;
            }
}

// ---------------- fallback (only if ws too small): f32 tiled, on-the-fly quant ----------------
__global__ void k_fallback(const float* __restrict__ x, const float* __restrict__ w,
                           const double* __restrict__ sc, float* __restrict__ out) {
    const int row0 = blockIdx.x * 16;
    const int col0 = blockIdx.y * 16;
    const int e = row0 / TT;
    __shared__ float xs[16][17];
    __shared__ float wq[16][17];
    const double scale = sc[0];
    const float s = (float)sc[1];
    const int tx = threadIdx.x, ty = threadIdx.y;
    const float* wbase = w + ((size_t)e * ND + col0) * KD;
    float acc = 0.f;
    for (int k0 = 0; k0 < KD; k0 += 16) {
        xs[ty][tx] = x[(size_t)(row0 + ty) * KD + k0 + tx];
        const float wv = wbase[(size_t)ty * KD + k0 + tx];
        wq[ty][tx] = (float)fmin(fmax(rint((double)wv * scale), -1.0), 1.0);
        __syncthreads();
#pragma unroll
        for (int kk = 0; kk < 16; ++kk) acc += xs[ty][kk] * wq[tx][kk];
        __syncthreads();
    }
    out[(size_t)(row0 + ty) * ND + col0 + tx] = acc * s;
}

// ---------------- launch ----------------
extern "C" void kernel_launch(void* const* d_in, const int* in_sizes, int n_in,
                              void* d_out, int out_size, void* d_ws, size_t ws_size,
                              hipStream_t stream) {
    const float* x = (const float*)d_in[0];
    const float* w = (const float*)d_in[1];
    float* out = (float*)d_out;

    double* part = (double*)d_ws;                       // 2048 * 8 B
    double* sc   = (double*)((char*)d_ws + 16384);      // [0]=scale, [1]=1/scale

    const size_t need = 65536 + NX * 2 + NW * 2;        // ~320 MiB

    hipLaunchKernelGGL(k_abs_partial, dim3(2048), dim3(256), 0, stream, w, part);
    hipLaunchKernelGGL(k_finalize,   dim3(1),    dim3(256), 0, stream, part, sc);

    if (ws_size >= need) {
        f16* xh = (f16*)((char*)d_ws + 65536);
        f16* qh = (f16*)((char*)d_ws + 65536 + NX * 2);
        hipLaunchKernelGGL(k_quant, dim3(2048), dim3(256), 0, stream, w, sc, qh);
        hipLaunchKernelGGL(k_xconv, dim3(2048), dim3(256), 0, stream, x, xh);
        hipLaunchKernelGGL(k_gemm,  dim3(NE * (TT / 256) * (ND / 256)), dim3(512), 0, stream,
                           xh, qh, sc, out);
    } else {
        dim3 grid(MT / 16, ND / 16);
        hipLaunchKernelGGL(k_fallback, grid, dim3(16, 16), 0, stream, x, w, sc, out);
    }
}